// Round 1
// baseline (875.861 us; speedup 1.0000x reference)
//
#include <hip/hip_runtime.h>

constexpr int Bc = 32, Tc = 2048, Hc = 512;

typedef _Float16 f16;
typedef _Float16 f16x8 __attribute__((ext_vector_type(8)));
typedef float f32x4 __attribute__((ext_vector_type(4)));

__device__ __forceinline__ void gload_lds16(const void* g, void* l) {
  __builtin_amdgcn_global_load_lds(
      (const __attribute__((address_space(1))) void*)g,
      (__attribute__((address_space(3))) void*)l, 16, 0, 0);
}

// ---------- transpose + f32->f16 convert for x/t: [b][t][h] -> [b][h][t] ----------
__global__ __launch_bounds__(256) void cvt_bth(const float* __restrict__ xin,
                                               const float* __restrict__ tin,
                                               f16* __restrict__ xo,
                                               f16* __restrict__ to) {
  __shared__ f16 tile[64][65];
  const int tid = threadIdx.x;
  const int c = tid & 63, r0 = tid >> 6;
  const int t0 = blockIdx.x * 64, h0 = blockIdx.y * 64;
  int z = blockIdx.z;
  const float* src;
  f16* dst;
  if (z < Bc) { src = xin; dst = xo; } else { src = tin; dst = to; z -= Bc; }
  src += (size_t)z * Tc * Hc;
  dst += (size_t)z * Hc * Tc;
#pragma unroll
  for (int rr = 0; rr < 64; rr += 4)
    tile[rr + r0][c] = (f16)src[(size_t)(t0 + rr + r0) * Hc + h0 + c];
  __syncthreads();
#pragma unroll
  for (int rr = 0; rr < 64; rr += 4)
    dst[(size_t)(h0 + rr + r0) * Tc + t0 + c] = tile[c][rr + r0];
}

// ---------- transpose + convert for the three TxT kernels: [t][s] -> [s][t] ----------
__global__ __launch_bounds__(256) void cvt_tt(const float* __restrict__ kx,
                                              const float* __restrict__ kt,
                                              const float* __restrict__ ka,
                                              f16* __restrict__ ox,
                                              f16* __restrict__ ot,
                                              f16* __restrict__ oa) {
  __shared__ f16 tile[64][65];
  const int tid = threadIdx.x;
  const int c = tid & 63, r0 = tid >> 6;
  const int t0 = blockIdx.x * 64, s0 = blockIdx.y * 64;
  const float* src = blockIdx.z == 0 ? kx : (blockIdx.z == 1 ? kt : ka);
  f16* dst = blockIdx.z == 0 ? ox : (blockIdx.z == 1 ? ot : oa);
#pragma unroll
  for (int rr = 0; rr < 64; rr += 4)
    tile[rr + r0][c] = (f16)src[(size_t)(t0 + rr + r0) * Tc + s0 + c];
  __syncthreads();
#pragma unroll
  for (int rr = 0; rr < 64; rr += 4)
    dst[(size_t)(s0 + rr + r0) * Tc + t0 + c] = tile[c][rr + r0];
}

// ---------- gemm_bt: C[m][n] = sum_k A[m][k]*B[n][k], A:[M][K] B:[N][K] f16, K=2048 ----------
// MODE 0: A=XhT[b], B=KxT, C=G_t[b] f16 = tanh(acc + bias_x[col])
// MODE 1: A=ThT[b], B=KtT, C=D_t[b] f16 = lam[row]*G + (1-lam[row])*tanh(acc + bias_t[col])
// MODE 2: A=KaT,    B=D_t[b], C=out[b] f32 = acc   (out layout [b][s'][h])
template <int MODE>
__global__ __launch_bounds__(256) void gemm_k(const f16* __restrict__ A,
                                              const f16* __restrict__ Bm,
                                              void* __restrict__ Cout,
                                              const f16* __restrict__ Gprev,
                                              const float* __restrict__ bias,
                                              const float* __restrict__ lambd) {
  constexpr int BK = 32;
  __shared__ f16 As[128][BK];
  __shared__ f16 Bs[128][BK];
  const int tid = threadIdx.x;
  const int lane = tid & 63;
  const int w = tid >> 6;
  const int wr = w >> 1, wc = w & 1;
  const int b = blockIdx.z;
  const int n0 = blockIdx.x * 128;
  const int m0 = blockIdx.y * 128;
  const size_t HT = (size_t)Hc * Tc;

  const f16* Ap = A + (MODE == 2 ? (size_t)0 : (size_t)b * HT) + (size_t)m0 * Tc;
  const f16* Bp = Bm + (MODE == 2 ? (size_t)b * HT : (size_t)0) + (size_t)n0 * Tc;

  // staging: thread stages one 16B chunk; LDS dest = wave-uniform base + lane*16
  const int srow = w * 16 + (lane >> 2);
  const int scol = (lane & 3) * 8;
  const f16* ga = Ap + (size_t)srow * Tc + scol;
  const f16* gb = Bp + (size_t)srow * Tc + scol;
  char* la = (char*)(&As[0][0]) + w * 1024;
  char* lb = (char*)(&Bs[0][0]) + w * 1024;

  f32x4 acc[4][4];
#pragma unroll
  for (int i = 0; i < 4; ++i)
#pragma unroll
    for (int j = 0; j < 4; ++j) acc[i][j] = {0.f, 0.f, 0.f, 0.f};

  const int l15 = lane & 15, kg = lane >> 4;

  for (int kt = 0; kt < Tc / BK; ++kt) {
    const int k0 = kt * BK;
    __syncthreads();  // previous iter's reads done before overwrite
    gload_lds16(ga + k0, la);
    gload_lds16(ga + (size_t)64 * Tc + k0, la + 4096);
    gload_lds16(gb + k0, lb);
    gload_lds16(gb + (size_t)64 * Tc + k0, lb + 4096);
    __syncthreads();  // drains vmcnt(0): staged data visible

    f16x8 af[4], bf[4];
#pragma unroll
    for (int i = 0; i < 4; ++i)
      af[i] = *(const f16x8*)(&As[wr * 64 + i * 16 + l15][kg * 8]);
#pragma unroll
    for (int j = 0; j < 4; ++j)
      bf[j] = *(const f16x8*)(&Bs[wc * 64 + j * 16 + l15][kg * 8]);
#pragma unroll
    for (int i = 0; i < 4; ++i)
#pragma unroll
      for (int j = 0; j < 4; ++j)
        acc[i][j] = __builtin_amdgcn_mfma_f32_16x16x32_f16(af[i], bf[j], acc[i][j], 0, 0, 0);
  }

  // epilogue: D frag mapping col=lane&15, row=(lane>>4)*4+r  [m89-verified]
#pragma unroll
  for (int i = 0; i < 4; ++i) {
#pragma unroll
    for (int r = 0; r < 4; ++r) {
      const int row = m0 + wr * 64 + i * 16 + kg * 4 + r;
#pragma unroll
      for (int j = 0; j < 4; ++j) {
        const int col = n0 + wc * 64 + j * 16 + l15;
        const float v = acc[i][j][r];
        if constexpr (MODE == 0) {
          f16* C = (f16*)Cout;
          C[(size_t)b * HT + (size_t)row * Tc + col] = (f16)tanhf(v + bias[col]);
        } else if constexpr (MODE == 1) {
          f16* C = (f16*)Cout;
          const size_t idx = (size_t)b * HT + (size_t)row * Tc + col;
          const float g = (float)Gprev[idx];
          const float lam = lambd[row];
          C[idx] = (f16)(lam * g + (1.f - lam) * tanhf(v + bias[col]));
        } else {
          float* C = (float*)Cout;
          C[(size_t)b * HT + (size_t)row * Hc + col] = v;
        }
      }
    }
  }
}

// ---------- in-place column softmax over s' of L[b][s'][h] ----------
__global__ __launch_bounds__(256) void softmax_k(float* __restrict__ L) {
  __shared__ float sm[4][64], ss[4][64];
  const int tid = threadIdx.x;
  const int c = tid & 63, seg = tid >> 6;
  const int b = blockIdx.x >> 3, hg = blockIdx.x & 7;
  const int h = hg * 64 + c;
  float* col = L + (size_t)b * Tc * Hc + h;
  const int sBase = seg * (Tc / 4);
  float m = -3.0e38f, s = 0.f;
#pragma unroll 4
  for (int i = 0; i < Tc / 4; ++i) {
    const float v = col[(size_t)(sBase + i) * Hc];
    const float nm = fmaxf(m, v);
    s = s * expf(m - nm) + expf(v - nm);
    m = nm;
  }
  sm[seg][c] = m;
  ss[seg][c] = s;
  __syncthreads();
  const float M = fmaxf(fmaxf(sm[0][c], sm[1][c]), fmaxf(sm[2][c], sm[3][c]));
  const float S = ss[0][c] * expf(sm[0][c] - M) + ss[1][c] * expf(sm[1][c] - M) +
                  ss[2][c] * expf(sm[2][c] - M) + ss[3][c] * expf(sm[3][c] - M);
  const float inv = 1.f / S;
#pragma unroll 4
  for (int i = 0; i < Tc / 4; ++i) {
    const size_t idx = (size_t)(sBase + i) * Hc;
    col[idx] = expf(col[idx] - M) * inv;
  }
}

extern "C" void kernel_launch(void* const* d_in, const int* in_sizes, int n_in,
                              void* d_out, int out_size, void* d_ws, size_t ws_size,
                              hipStream_t stream) {
  const float* x  = (const float*)d_in[0];
  const float* tt = (const float*)d_in[1];
  const float* kx = (const float*)d_in[2];
  const float* kt = (const float*)d_in[3];
  const float* ka = (const float*)d_in[4];
  const float* bx = (const float*)d_in[5];
  const float* bt = (const float*)d_in[6];
  const float* lm = (const float*)d_in[7];
  float* out = (float*)d_out;

  const size_t NBHT = (size_t)Bc * Hc * Tc;  // 33,554,432 elements

  // d_out doubles as scratch for the f16-transposed inputs until gemm3 overwrites it
  f16* XhT = (f16*)d_out;
  f16* ThT = XhT + NBHT;

  // workspace layout: G_t(64MiB) D_t(64MiB) KxT(8) KtT(8) KaT(8)  -> ~152 MiB
  f16* Gt  = (f16*)d_ws;
  f16* Dt  = Gt + NBHT;
  f16* KxT = Dt + NBHT;
  f16* KtT = KxT + (size_t)Tc * Tc;
  f16* KaT = KtT + (size_t)Tc * Tc;

  cvt_bth<<<dim3(Tc / 64, Hc / 64, Bc * 2), 256, 0, stream>>>(x, tt, XhT, ThT);
  cvt_tt<<<dim3(Tc / 64, Tc / 64, 3), 256, 0, stream>>>(kx, kt, ka, KxT, KtT, KaT);
  gemm_k<0><<<dim3(Tc / 128, Hc / 128, Bc), 256, 0, stream>>>(XhT, KxT, Gt, nullptr, bx, nullptr);
  gemm_k<1><<<dim3(Tc / 128, Hc / 128, Bc), 256, 0, stream>>>(ThT, KtT, Dt, Gt, bt, lm);
  gemm_k<2><<<dim3(Hc / 128, Tc / 128, Bc), 256, 0, stream>>>(KaT, Dt, out, nullptr, nullptr, nullptr);
  softmax_k<<<dim3(Bc * Hc / 64), 256, 0, stream>>>(out);
}

// Round 2
// 735.799 us; speedup vs baseline: 1.1904x; 1.1904x over previous
//
#include <hip/hip_runtime.h>

constexpr int Bc = 32, Tc = 2048, Hc = 512;

typedef _Float16 f16;
typedef _Float16 f16x8 __attribute__((ext_vector_type(8)));
typedef float f32x4 __attribute__((ext_vector_type(4)));

__device__ __forceinline__ void gload_lds16(const void* g, void* l) {
  __builtin_amdgcn_global_load_lds(
      (const __attribute__((address_space(1))) void*)g,
      (__attribute__((address_space(3))) void*)l, 16, 0, 0);
}

__device__ __forceinline__ void block_barrier() {
  __builtin_amdgcn_sched_barrier(0);
  asm volatile("" ::: "memory");
  __builtin_amdgcn_s_barrier();
  asm volatile("" ::: "memory");
  __builtin_amdgcn_sched_barrier(0);
}

// ---------- transpose + f32->f16 convert for x/t: [b][t][h] -> [b][h][t] ----------
__global__ __launch_bounds__(256) void cvt_bth(const float* __restrict__ xin,
                                               const float* __restrict__ tin,
                                               f16* __restrict__ xo,
                                               f16* __restrict__ to) {
  __shared__ f16 tile[64][65];
  const int tid = threadIdx.x;
  const int c = tid & 63, r0 = tid >> 6;
  const int t0 = blockIdx.x * 64, h0 = blockIdx.y * 64;
  int z = blockIdx.z;
  const float* src;
  f16* dst;
  if (z < Bc) { src = xin; dst = xo; } else { src = tin; dst = to; z -= Bc; }
  src += (size_t)z * Tc * Hc;
  dst += (size_t)z * Hc * Tc;
#pragma unroll
  for (int rr = 0; rr < 64; rr += 4)
    tile[rr + r0][c] = (f16)src[(size_t)(t0 + rr + r0) * Hc + h0 + c];
  __syncthreads();
#pragma unroll
  for (int rr = 0; rr < 64; rr += 4)
    dst[(size_t)(h0 + rr + r0) * Tc + t0 + c] = tile[c][rr + r0];
}

// ---------- transpose + convert for the three TxT kernels: [t][s] -> [s][t] ----------
__global__ __launch_bounds__(256) void cvt_tt(const float* __restrict__ kx,
                                              const float* __restrict__ kt,
                                              const float* __restrict__ ka,
                                              f16* __restrict__ ox,
                                              f16* __restrict__ ot,
                                              f16* __restrict__ oa) {
  __shared__ f16 tile[64][65];
  const int tid = threadIdx.x;
  const int c = tid & 63, r0 = tid >> 6;
  const int t0 = blockIdx.x * 64, s0 = blockIdx.y * 64;
  const float* src = blockIdx.z == 0 ? kx : (blockIdx.z == 1 ? kt : ka);
  f16* dst = blockIdx.z == 0 ? ox : (blockIdx.z == 1 ? ot : oa);
#pragma unroll
  for (int rr = 0; rr < 64; rr += 4)
    tile[rr + r0][c] = (f16)src[(size_t)(t0 + rr + r0) * Tc + s0 + c];
  __syncthreads();
#pragma unroll
  for (int rr = 0; rr < 64; rr += 4)
    dst[(size_t)(s0 + rr + r0) * Tc + t0 + c] = tile[c][rr + r0];
}

// ---------- 256x256 deep-pipelined GEMM: C[m][n] = sum_k A[m][k]*B[n][k] ----------
// 8 waves (2x4), BK=32, 3 LDS buffers, counted vmcnt, XOR-swizzled LDS.
// MODE 0: A=XhT flat[16384][2048], B=KxT[2048][2048], C=Gt f16 = tanh(acc+bias[col])
// MODE 1: A=ThT, B=KtT, C=Dt f16 = lam*G + (1-lam)*tanh(acc+bias[col])
// MODE 2: A=KaT[2048][2048], B=Dt[b][512][2048], C=out[b][s'][h] f32
template <int MODE>
__global__ __launch_bounds__(512, 2) void gemm_k(const f16* __restrict__ A,
                                                 const f16* __restrict__ Bm,
                                                 void* __restrict__ Cout,
                                                 const f16* __restrict__ Gprev,
                                                 const float* __restrict__ bias,
                                                 const float* __restrict__ lambd) {
  extern __shared__ char smem[];
  constexpr int BK = 32, NT = Tc / BK;            // 64 K-tiles
  constexpr int ABYTES = 256 * BK * 2;            // 16384 B per buffer
  const int tid = threadIdx.x;
  const int lane = tid & 63, w = tid >> 6;
  const int wr = w >> 2, wc = w & 3;              // 2 x 4 wave grid
  const int l15 = lane & 15, kg = lane >> 4;

  // grid: 512 blocks, XCD-bijective swizzle (512 % 8 == 0)
  int id = (int)blockIdx.x;
  id = (id & 7) * ((int)gridDim.x >> 3) + (id >> 3);
  int b, m0, n0;
  if constexpr (MODE == 2) {
    b = id >> 4; m0 = ((id >> 1) & 7) * 256; n0 = (id & 1) * 256;
  } else {
    b = 0; m0 = (id >> 3) * 256; n0 = (id & 7) * 256;
  }

  const size_t K = Tc;
  const size_t HT = (size_t)Hc * Tc;
  const f16* Ag = A + (size_t)m0 * K;
  const f16* Bg = Bm + (MODE == 2 ? (size_t)b * HT : (size_t)0) + (size_t)n0 * K;

  // staging: wave w call j stages tile rows 16*(2w+j)..+15 (1 KiB linear LDS);
  // global source pre-swizzled: chunk c = (lane&3) ^ ((lane>>3)&3)
  const int r4 = lane >> 2;
  const int cswz = ((lane & 3) ^ ((lane >> 3) & 3)) * 8;
  const int sr0 = (w * 2 + 0) * 16 + r4, sr1 = (w * 2 + 1) * 16 + r4;
  const f16* gA0 = Ag + (size_t)sr0 * K + cswz;
  const f16* gA1 = Ag + (size_t)sr1 * K + cswz;
  const f16* gB0 = Bg + (size_t)sr0 * K + cswz;
  const f16* gB1 = Bg + (size_t)sr1 * K + cswz;
  char* lA = smem;                 // 3 * 16384
  char* lB = smem + 3 * ABYTES;    // 3 * 16384
  const int lo0 = (w * 2 + 0) * 1024, lo1 = (w * 2 + 1) * 1024;

  // ds_read fragment addressing, swizzled: chunk' = kg ^ ((l15>>1)&3) (i*16 drops out)
  const int xk = (kg ^ ((l15 >> 1) & 3)) * 16;
  const int aoff = (wr * 128 + l15) * 64 + xk;    // + i*1024 per M-frag
  const int boff = (wc * 64 + l15) * 64 + xk;     // + j*1024 per N-frag

  f32x4 acc[8][4];
#pragma unroll
  for (int i = 0; i < 8; ++i)
#pragma unroll
    for (int j = 0; j < 4; ++j) acc[i][j] = {0.f, 0.f, 0.f, 0.f};

  // prologue: stage tiles 0 and 1
  {
    char* d0A = lA + 0 * ABYTES; char* d0B = lB + 0 * ABYTES;
    char* d1A = lA + 1 * ABYTES; char* d1B = lB + 1 * ABYTES;
    gload_lds16(gA0, d0A + lo0); gload_lds16(gA1, d0A + lo1);
    gload_lds16(gB0, d0B + lo0); gload_lds16(gB1, d0B + lo1);
    gload_lds16(gA0 + BK, d1A + lo0); gload_lds16(gA1 + BK, d1A + lo1);
    gload_lds16(gB0 + BK, d1B + lo0); gload_lds16(gB1 + BK, d1B + lo1);
  }
  asm volatile("s_waitcnt vmcnt(4)" ::: "memory");  // tile 0 landed; tile 1 in flight
  block_barrier();

  for (int t = 0; t < NT; ++t) {
    char* curA = lA + (t % 3) * ABYTES;
    char* curB = lB + (t % 3) * ABYTES;
    const int tn = t + 2;
    char* nA = lA + (tn % 3) * ABYTES;
    char* nB = lB + (tn % 3) * ABYTES;

    // ---- phase 1: B-frags + A-frags 0..3, stage A(t+2) ----
    f16x8 bf[4], af[4];
#pragma unroll
    for (int j = 0; j < 4; ++j) bf[j] = *(const f16x8*)(curB + boff + j * 1024);
#pragma unroll
    for (int i = 0; i < 4; ++i) af[i] = *(const f16x8*)(curA + aoff + i * 1024);
    if (tn < NT) {
      gload_lds16(gA0 + (size_t)tn * BK, nA + lo0);
      gload_lds16(gA1 + (size_t)tn * BK, nA + lo1);
    }
    block_barrier();
    asm volatile("s_waitcnt lgkmcnt(0)" ::: "memory");
    __builtin_amdgcn_sched_barrier(0);
    __builtin_amdgcn_s_setprio(1);
#pragma unroll
    for (int i = 0; i < 4; ++i)
#pragma unroll
      for (int j = 0; j < 4; ++j)
        acc[i][j] = __builtin_amdgcn_mfma_f32_16x16x32_f16(af[i], bf[j], acc[i][j], 0, 0, 0);
    __builtin_amdgcn_s_setprio(0);
    block_barrier();

    // ---- phase 2: A-frags 4..7, stage B(t+2), end-of-tile counted vmcnt ----
    f16x8 ag[4];
#pragma unroll
    for (int i = 0; i < 4; ++i) ag[i] = *(const f16x8*)(curA + aoff + (4 + i) * 1024);
    if (tn < NT) {
      gload_lds16(gB0 + (size_t)tn * BK, nB + lo0);
      gload_lds16(gB1 + (size_t)tn * BK, nB + lo1);
    }
    if (t < NT - 2) {
      asm volatile("s_waitcnt vmcnt(4)" ::: "memory");  // tile t+1 landed; t+2 in flight
    } else {
      asm volatile("s_waitcnt vmcnt(0)" ::: "memory");  // drain at the tail
    }
    block_barrier();
    asm volatile("s_waitcnt lgkmcnt(0)" ::: "memory");
    __builtin_amdgcn_sched_barrier(0);
    __builtin_amdgcn_s_setprio(1);
#pragma unroll
    for (int i = 0; i < 4; ++i)
#pragma unroll
      for (int j = 0; j < 4; ++j)
        acc[4 + i][j] = __builtin_amdgcn_mfma_f32_16x16x32_f16(ag[i], bf[j], acc[4 + i][j], 0, 0, 0);
    __builtin_amdgcn_s_setprio(0);
    block_barrier();
  }

  // ---- epilogue ----
#pragma unroll
  for (int i = 0; i < 8; ++i) {
#pragma unroll
    for (int r = 0; r < 4; ++r) {
      const int gr = m0 + wr * 128 + i * 16 + kg * 4 + r;
#pragma unroll
      for (int j = 0; j < 4; ++j) {
        const int gc = n0 + wc * 64 + j * 16 + l15;
        const float v = acc[i][j][r];
        if constexpr (MODE == 0) {
          f16* C = (f16*)Cout;
          C[(size_t)gr * Tc + gc] = (f16)tanhf(v + bias[gc]);
        } else if constexpr (MODE == 1) {
          f16* C = (f16*)Cout;
          const size_t idx = (size_t)gr * Tc + gc;
          const float g = (float)Gprev[idx];
          const float lam = lambd[gr & 511];
          C[idx] = (f16)(lam * g + (1.f - lam) * tanhf(v + bias[gc]));
        } else {
          float* C = (float*)Cout;
          C[(size_t)b * Tc * Hc + (size_t)gr * Hc + gc] = v;
        }
      }
    }
  }
}

// ---------- in-place column softmax over s' of L[b][s'][h] ----------
__global__ __launch_bounds__(256) void softmax_k(float* __restrict__ L) {
  __shared__ float sm[4][64], ss[4][64];
  const int tid = threadIdx.x;
  const int c = tid & 63, seg = tid >> 6;
  const int b = blockIdx.x >> 3, hg = blockIdx.x & 7;
  const int h = hg * 64 + c;
  float* col = L + (size_t)b * Tc * Hc + h;
  const int sBase = seg * (Tc / 4);
  float m = -3.0e38f, s = 0.f;
#pragma unroll 4
  for (int i = 0; i < Tc / 4; ++i) {
    const float v = col[(size_t)(sBase + i) * Hc];
    const float nm = fmaxf(m, v);
    s = s * expf(m - nm) + expf(v - nm);
    m = nm;
  }
  sm[seg][c] = m;
  ss[seg][c] = s;
  __syncthreads();
  const float M = fmaxf(fmaxf(sm[0][c], sm[1][c]), fmaxf(sm[2][c], sm[3][c]));
  const float S = ss[0][c] * expf(sm[0][c] - M) + ss[1][c] * expf(sm[1][c] - M) +
                  ss[2][c] * expf(sm[2][c] - M) + ss[3][c] * expf(sm[3][c] - M);
  const float inv = 1.f / S;
#pragma unroll 4
  for (int i = 0; i < Tc / 4; ++i) {
    const size_t idx = (size_t)(sBase + i) * Hc;
    col[idx] = expf(col[idx] - M) * inv;
  }
}

extern "C" void kernel_launch(void* const* d_in, const int* in_sizes, int n_in,
                              void* d_out, int out_size, void* d_ws, size_t ws_size,
                              hipStream_t stream) {
  const float* x  = (const float*)d_in[0];
  const float* tt = (const float*)d_in[1];
  const float* kx = (const float*)d_in[2];
  const float* kt = (const float*)d_in[3];
  const float* ka = (const float*)d_in[4];
  const float* bx = (const float*)d_in[5];
  const float* bt = (const float*)d_in[6];
  const float* lm = (const float*)d_in[7];
  float* out = (float*)d_out;

  const size_t NBHT = (size_t)Bc * Hc * Tc;  // 33,554,432 elements

  // d_out doubles as scratch for the f16-transposed inputs until gemm3 overwrites it
  f16* XhT = (f16*)d_out;
  f16* ThT = XhT + NBHT;

  // workspace: Gt(64MiB) Dt(64MiB) KxT(8) KtT(8) KaT(8)
  f16* Gt  = (f16*)d_ws;
  f16* Dt  = Gt + NBHT;
  f16* KxT = Dt + NBHT;
  f16* KtT = KxT + (size_t)Tc * Tc;
  f16* KaT = KtT + (size_t)Tc * Tc;

  constexpr int LDS_BYTES = 6 * 256 * 32 * 2;  // 98304
  (void)hipFuncSetAttribute(reinterpret_cast<const void*>(gemm_k<0>),
                            hipFuncAttributeMaxDynamicSharedMemorySize, LDS_BYTES);
  (void)hipFuncSetAttribute(reinterpret_cast<const void*>(gemm_k<1>),
                            hipFuncAttributeMaxDynamicSharedMemorySize, LDS_BYTES);
  (void)hipFuncSetAttribute(reinterpret_cast<const void*>(gemm_k<2>),
                            hipFuncAttributeMaxDynamicSharedMemorySize, LDS_BYTES);

  cvt_bth<<<dim3(Tc / 64, Hc / 64, Bc * 2), 256, 0, stream>>>(x, tt, XhT, ThT);
  cvt_tt<<<dim3(Tc / 64, Tc / 64, 3), 256, 0, stream>>>(kx, kt, ka, KxT, KtT, KaT);
  // modes 0/1: M = 32*512 = 16384 merged over batch, N = 2048 -> 64x8 = 512 blocks
  gemm_k<0><<<512, 512, LDS_BYTES, stream>>>(XhT, KxT, Gt, nullptr, bx, nullptr);
  gemm_k<1><<<512, 512, LDS_BYTES, stream>>>(ThT, KtT, Dt, Gt, bt, lm);
  // mode 2: per batch M = 2048, N = 512 -> 8x2 x 32 = 512 blocks
  gemm_k<2><<<512, 512, LDS_BYTES, stream>>>(KaT, Dt, out, nullptr, nullptr, nullptr);
  softmax_k<<<dim3(Bc * Hc / 64), 256, 0, stream>>>(out);
}

// Round 3
// 644.737 us; speedup vs baseline: 1.3585x; 1.1412x over previous
//
#include <hip/hip_runtime.h>

constexpr int Bc = 32, Tc = 2048, Hc = 512;

typedef _Float16 f16;
typedef _Float16 f16x8 __attribute__((ext_vector_type(8)));
typedef float f32x4 __attribute__((ext_vector_type(4)));

__device__ __forceinline__ void gload_lds16(const void* g, void* l) {
  __builtin_amdgcn_global_load_lds(
      (const __attribute__((address_space(1))) void*)g,
      (__attribute__((address_space(3))) void*)l, 16, 0, 0);
}

__device__ __forceinline__ void block_barrier() {
  __builtin_amdgcn_sched_barrier(0);
  asm volatile("" ::: "memory");
  __builtin_amdgcn_s_barrier();
  asm volatile("" ::: "memory");
  __builtin_amdgcn_sched_barrier(0);
}

// ---------- transpose + f32->f16 convert for x/t: [b][t][h] -> [b][h][t] ----------
__global__ __launch_bounds__(256) void cvt_bth(const float* __restrict__ xin,
                                               const float* __restrict__ tin,
                                               f16* __restrict__ xo,
                                               f16* __restrict__ to) {
  __shared__ f16 tile[64][65];
  const int tid = threadIdx.x;
  const int c = tid & 63, r0 = tid >> 6;
  const int t0 = blockIdx.x * 64, h0 = blockIdx.y * 64;
  int z = blockIdx.z;
  const float* src;
  f16* dst;
  if (z < Bc) { src = xin; dst = xo; } else { src = tin; dst = to; z -= Bc; }
  src += (size_t)z * Tc * Hc;
  dst += (size_t)z * Hc * Tc;
#pragma unroll
  for (int rr = 0; rr < 64; rr += 4)
    tile[rr + r0][c] = (f16)src[(size_t)(t0 + rr + r0) * Hc + h0 + c];
  __syncthreads();
#pragma unroll
  for (int rr = 0; rr < 64; rr += 4)
    dst[(size_t)(h0 + rr + r0) * Tc + t0 + c] = tile[c][rr + r0];
}

// ---------- transpose + convert for the three TxT kernels: [t][s] -> [s][t] ----------
__global__ __launch_bounds__(256) void cvt_tt(const float* __restrict__ kx,
                                              const float* __restrict__ kt,
                                              const float* __restrict__ ka,
                                              f16* __restrict__ ox,
                                              f16* __restrict__ ot,
                                              f16* __restrict__ oa) {
  __shared__ f16 tile[64][65];
  const int tid = threadIdx.x;
  const int c = tid & 63, r0 = tid >> 6;
  const int t0 = blockIdx.x * 64, s0 = blockIdx.y * 64;
  const float* src = blockIdx.z == 0 ? kx : (blockIdx.z == 1 ? kt : ka);
  f16* dst = blockIdx.z == 0 ? ox : (blockIdx.z == 1 ? ot : oa);
#pragma unroll
  for (int rr = 0; rr < 64; rr += 4)
    tile[rr + r0][c] = (f16)src[(size_t)(t0 + rr + r0) * Tc + s0 + c];
  __syncthreads();
#pragma unroll
  for (int rr = 0; rr < 64; rr += 4)
    dst[(size_t)(s0 + rr + r0) * Tc + t0 + c] = tile[c][rr + r0];
}

// ---------- 256x256 deep-pipelined GEMM: C[m][n] = sum_k A[m][k]*B[n][k] ----------
// 8 waves (2x4), BK=32, 3 LDS buffers, counted vmcnt, XOR-swizzled LDS.
// MODE 0: A=XhT flat[16384][2048], B=KxT[2048][2048], C=Gt f16 = tanh(acc+bias[col])
// MODE 1: A=ThT, B=KtT, C=Dt f16 = lam*G + (1-lam)*tanh(acc+bias[col])
// MODE 2: A=KaT[2048][2048], B=Dt[b][512][2048], C=out[b][s'][h] f32 = exp(acc),
//         plus deterministic per-block column sums -> psums[b][m0/256][h]
template <int MODE>
__global__ __launch_bounds__(512, 2) void gemm_k(const f16* __restrict__ A,
                                                 const f16* __restrict__ Bm,
                                                 void* __restrict__ Cout,
                                                 const f16* __restrict__ Gprev,
                                                 const float* __restrict__ bias,
                                                 const float* __restrict__ lambd,
                                                 float* __restrict__ psums) {
  extern __shared__ char smem[];
  constexpr int BK = 32, NT = Tc / BK;            // 64 K-tiles
  constexpr int ABYTES = 256 * BK * 2;            // 16384 B per buffer
  const int tid = threadIdx.x;
  const int lane = tid & 63, w = tid >> 6;
  const int wr = w >> 2, wc = w & 3;              // 2 x 4 wave grid
  const int l15 = lane & 15, kg = lane >> 4;

  // grid: 512 blocks, XCD-bijective swizzle (512 % 8 == 0)
  int id = (int)blockIdx.x;
  id = (id & 7) * ((int)gridDim.x >> 3) + (id >> 3);
  int b, m0, n0;
  if constexpr (MODE == 2) {
    b = id >> 4; m0 = ((id >> 1) & 7) * 256; n0 = (id & 1) * 256;
  } else {
    b = 0; m0 = (id >> 3) * 256; n0 = (id & 7) * 256;
  }

  const size_t K = Tc;
  const size_t HT = (size_t)Hc * Tc;
  const f16* Ag = A + (size_t)m0 * K;
  const f16* Bg = Bm + (MODE == 2 ? (size_t)b * HT : (size_t)0) + (size_t)n0 * K;

  // staging: wave w call j stages tile rows 16*(2w+j)..+15 (1 KiB linear LDS);
  // global source pre-swizzled: chunk c = (lane&3) ^ ((lane>>3)&3)
  const int r4 = lane >> 2;
  const int cswz = ((lane & 3) ^ ((lane >> 3) & 3)) * 8;
  const int sr0 = (w * 2 + 0) * 16 + r4, sr1 = (w * 2 + 1) * 16 + r4;
  const f16* gA0 = Ag + (size_t)sr0 * K + cswz;
  const f16* gA1 = Ag + (size_t)sr1 * K + cswz;
  const f16* gB0 = Bg + (size_t)sr0 * K + cswz;
  const f16* gB1 = Bg + (size_t)sr1 * K + cswz;
  char* lA = smem;                 // 3 * 16384
  char* lB = smem + 3 * ABYTES;    // 3 * 16384
  const int lo0 = (w * 2 + 0) * 1024, lo1 = (w * 2 + 1) * 1024;

  // ds_read fragment addressing, swizzled: chunk' = kg ^ ((l15>>1)&3) (i*16 drops out)
  const int xk = (kg ^ ((l15 >> 1) & 3)) * 16;
  const int aoff = (wr * 128 + l15) * 64 + xk;    // + i*1024 per M-frag
  const int boff = (wc * 64 + l15) * 64 + xk;     // + j*1024 per N-frag

  f32x4 acc[8][4];
#pragma unroll
  for (int i = 0; i < 8; ++i)
#pragma unroll
    for (int j = 0; j < 4; ++j) acc[i][j] = {0.f, 0.f, 0.f, 0.f};

  // prologue: stage tiles 0 and 1
  {
    char* d0A = lA + 0 * ABYTES; char* d0B = lB + 0 * ABYTES;
    char* d1A = lA + 1 * ABYTES; char* d1B = lB + 1 * ABYTES;
    gload_lds16(gA0, d0A + lo0); gload_lds16(gA1, d0A + lo1);
    gload_lds16(gB0, d0B + lo0); gload_lds16(gB1, d0B + lo1);
    gload_lds16(gA0 + BK, d1A + lo0); gload_lds16(gA1 + BK, d1A + lo1);
    gload_lds16(gB0 + BK, d1B + lo0); gload_lds16(gB1 + BK, d1B + lo1);
  }
  asm volatile("s_waitcnt vmcnt(4)" ::: "memory");  // tile 0 landed; tile 1 in flight
  block_barrier();

  for (int t = 0; t < NT; ++t) {
    char* curA = lA + (t % 3) * ABYTES;
    char* curB = lB + (t % 3) * ABYTES;
    const int tn = t + 2;
    char* nA = lA + (tn % 3) * ABYTES;
    char* nB = lB + (tn % 3) * ABYTES;

    // ---- phase 1: B-frags + A-frags 0..3, stage A(t+2) ----
    f16x8 bf[4], af[4];
#pragma unroll
    for (int j = 0; j < 4; ++j) bf[j] = *(const f16x8*)(curB + boff + j * 1024);
#pragma unroll
    for (int i = 0; i < 4; ++i) af[i] = *(const f16x8*)(curA + aoff + i * 1024);
    if (tn < NT) {
      gload_lds16(gA0 + (size_t)tn * BK, nA + lo0);
      gload_lds16(gA1 + (size_t)tn * BK, nA + lo1);
    }
    block_barrier();
    asm volatile("s_waitcnt lgkmcnt(0)" ::: "memory");
    __builtin_amdgcn_sched_barrier(0);
    __builtin_amdgcn_s_setprio(1);
#pragma unroll
    for (int i = 0; i < 4; ++i)
#pragma unroll
      for (int j = 0; j < 4; ++j)
        acc[i][j] = __builtin_amdgcn_mfma_f32_16x16x32_f16(af[i], bf[j], acc[i][j], 0, 0, 0);
    __builtin_amdgcn_s_setprio(0);
    block_barrier();

    // ---- phase 2: A-frags 4..7, stage B(t+2), end-of-tile counted vmcnt ----
    f16x8 ag[4];
#pragma unroll
    for (int i = 0; i < 4; ++i) ag[i] = *(const f16x8*)(curA + aoff + (4 + i) * 1024);
    if (tn < NT) {
      gload_lds16(gB0 + (size_t)tn * BK, nB + lo0);
      gload_lds16(gB1 + (size_t)tn * BK, nB + lo1);
    }
    if (t < NT - 2) {
      asm volatile("s_waitcnt vmcnt(4)" ::: "memory");  // tile t+1 landed; t+2 in flight
    } else {
      asm volatile("s_waitcnt vmcnt(0)" ::: "memory");  // drain at the tail
    }
    block_barrier();
    asm volatile("s_waitcnt lgkmcnt(0)" ::: "memory");
    __builtin_amdgcn_sched_barrier(0);
    __builtin_amdgcn_s_setprio(1);
#pragma unroll
    for (int i = 0; i < 4; ++i)
#pragma unroll
      for (int j = 0; j < 4; ++j)
        acc[4 + i][j] = __builtin_amdgcn_mfma_f32_16x16x32_f16(ag[i], bf[j], acc[4 + i][j], 0, 0, 0);
    __builtin_amdgcn_s_setprio(0);
    block_barrier();
  }

  // ---- epilogue ----
  float psum[4] = {0.f, 0.f, 0.f, 0.f};
#pragma unroll
  for (int i = 0; i < 8; ++i) {
#pragma unroll
    for (int r = 0; r < 4; ++r) {
      const int gr = m0 + wr * 128 + i * 16 + kg * 4 + r;
#pragma unroll
      for (int j = 0; j < 4; ++j) {
        const int gc = n0 + wc * 64 + j * 16 + l15;
        const float v = acc[i][j][r];
        if constexpr (MODE == 0) {
          f16* C = (f16*)Cout;
          C[(size_t)gr * Tc + gc] = (f16)tanhf(v + bias[gc]);
        } else if constexpr (MODE == 1) {
          f16* C = (f16*)Cout;
          const size_t idx = (size_t)gr * Tc + gc;
          const float g = (float)Gprev[idx];
          const float lam = lambd[gr & 511];
          C[idx] = (f16)(lam * g + (1.f - lam) * tanhf(v + bias[gc]));
        } else {
          // no-max softmax numerator: logits are O(1) (delta in (-1,1),
          // kernel_a ~ N(0,1/T)) so exp() cannot overflow; softmax is
          // shift-invariant so this matches the max-subtracted reference.
          float* C = (float*)Cout;
          const float e = expf(v);
          C[(size_t)b * Tc * Hc + (size_t)gr * Hc + gc] = e;
          psum[j] += e;
        }
      }
    }
  }
  if constexpr (MODE == 2) {
    // deterministic column-sum reduction: 8 partial rows x 256 cols, bijective slots
    float* ps = (float*)smem;  // K-loop LDS is dead past the final block_barrier
#pragma unroll
    for (int j = 0; j < 4; ++j)
      ps[(wr * 4 + kg) * 256 + (wc * 64 + j * 16 + l15)] = psum[j];
    __syncthreads();
    if (tid < 256) {
      float s = 0.f;
#pragma unroll
      for (int p = 0; p < 8; ++p) s += ps[p * 256 + tid];
      psums[((size_t)b * 8 + (m0 >> 8)) * Hc + n0 + tid] = s;
    }
  }
}

// ---------- normalize: out[b][s'][h] *= 1 / sum_p psums[b][p][h] ----------
__global__ __launch_bounds__(1024) void norm_k(float* __restrict__ L,
                                               const float* __restrict__ psums) {
  const int tid = threadIdx.x;
  const int q = tid & 15, seg = tid >> 4;        // 16 h-quads x 64 T-segments
  const int b = blockIdx.x >> 3, hg = blockIdx.x & 7;
  const int h = hg * 64 + q * 4;
  const float* P = psums + (size_t)b * 8 * Hc + h;
  float s0 = 0.f, s1 = 0.f, s2 = 0.f, s3 = 0.f;
#pragma unroll
  for (int p = 0; p < 8; ++p) {
    s0 += P[p * Hc + 0]; s1 += P[p * Hc + 1];
    s2 += P[p * Hc + 2]; s3 += P[p * Hc + 3];
  }
  const float i0 = 1.f / s0, i1 = 1.f / s1, i2 = 1.f / s2, i3 = 1.f / s3;
  float* base = L + (size_t)b * Tc * Hc + h;
#pragma unroll 4
  for (int i = 0; i < 32; ++i) {
    const size_t idx = (size_t)(seg * 32 + i) * Hc;
    float4 v = *(float4*)(base + idx);
    v.x *= i0; v.y *= i1; v.z *= i2; v.w *= i3;
    *(float4*)(base + idx) = v;
  }
}

extern "C" void kernel_launch(void* const* d_in, const int* in_sizes, int n_in,
                              void* d_out, int out_size, void* d_ws, size_t ws_size,
                              hipStream_t stream) {
  const float* x  = (const float*)d_in[0];
  const float* tt = (const float*)d_in[1];
  const float* kx = (const float*)d_in[2];
  const float* kt = (const float*)d_in[3];
  const float* ka = (const float*)d_in[4];
  const float* bx = (const float*)d_in[5];
  const float* bt = (const float*)d_in[6];
  const float* lm = (const float*)d_in[7];
  float* out = (float*)d_out;

  const size_t NBHT = (size_t)Bc * Hc * Tc;  // 33,554,432 elements

  // d_out doubles as scratch for the f16-transposed inputs until gemm3 overwrites it
  f16* XhT = (f16*)d_out;
  f16* ThT = XhT + NBHT;

  // workspace: Gt(64MiB) Dt(64MiB) KxT(8) KtT(8) KaT(8)
  f16* Gt  = (f16*)d_ws;
  f16* Dt  = Gt + NBHT;
  f16* KxT = Dt + NBHT;
  f16* KtT = KxT + (size_t)Tc * Tc;
  f16* KaT = KtT + (size_t)Tc * Tc;
  // psums[32][8][512] f32 (512 KiB) reuses KxT, which is dead after gemm_k<0>
  float* Ps = (float*)KxT;

  constexpr int LDS_BYTES = 6 * 256 * 32 * 2;  // 98304
  (void)hipFuncSetAttribute(reinterpret_cast<const void*>(gemm_k<0>),
                            hipFuncAttributeMaxDynamicSharedMemorySize, LDS_BYTES);
  (void)hipFuncSetAttribute(reinterpret_cast<const void*>(gemm_k<1>),
                            hipFuncAttributeMaxDynamicSharedMemorySize, LDS_BYTES);
  (void)hipFuncSetAttribute(reinterpret_cast<const void*>(gemm_k<2>),
                            hipFuncAttributeMaxDynamicSharedMemorySize, LDS_BYTES);

  cvt_bth<<<dim3(Tc / 64, Hc / 64, Bc * 2), 256, 0, stream>>>(x, tt, XhT, ThT);
  cvt_tt<<<dim3(Tc / 64, Tc / 64, 3), 256, 0, stream>>>(kx, kt, ka, KxT, KtT, KaT);
  // modes 0/1: M = 32*512 = 16384 merged over batch, N = 2048 -> 64x8 = 512 blocks
  gemm_k<0><<<512, 512, LDS_BYTES, stream>>>(XhT, KxT, Gt, nullptr, bx, nullptr, nullptr);
  gemm_k<1><<<512, 512, LDS_BYTES, stream>>>(ThT, KtT, Dt, Gt, bt, lm, nullptr);
  // mode 2: per batch M = 2048, N = 512 -> 8x2 x 32 = 512 blocks
  gemm_k<2><<<512, 512, LDS_BYTES, stream>>>(KaT, Dt, out, nullptr, nullptr, nullptr, Ps);
  norm_k<<<dim3(Bc * Hc / 64), 1024, 0, stream>>>(out, Ps);
}

// Round 5
// 588.382 us; speedup vs baseline: 1.4886x; 1.0958x over previous
//
#include <hip/hip_runtime.h>

constexpr int Bc = 32, Tc = 2048, Hc = 512;

typedef _Float16 f16;
typedef _Float16 f16x8 __attribute__((ext_vector_type(8)));
typedef float f32x4 __attribute__((ext_vector_type(4)));

__device__ __forceinline__ void gload_lds16(const void* g, void* l) {
  __builtin_amdgcn_global_load_lds(
      (const __attribute__((address_space(1))) void*)g,
      (__attribute__((address_space(3))) void*)l, 16, 0, 0);
}

__device__ __forceinline__ void block_barrier() {
  __builtin_amdgcn_sched_barrier(0);
  asm volatile("" ::: "memory");
  __builtin_amdgcn_s_barrier();
  asm volatile("" ::: "memory");
  __builtin_amdgcn_sched_barrier(0);
}

// hardware-exp math: v_exp_f32 is 2^x, ~1 ulp
__device__ __forceinline__ float fast_exp(float x) {
  return __builtin_amdgcn_exp2f(x * 1.4426950408889634f);
}
__device__ __forceinline__ float fast_tanh(float x) {
  const float z = __builtin_amdgcn_exp2f(x * 2.8853900817779268f);  // 2^(2x*log2e)=e^(2x)
  return (z - 1.0f) * __builtin_amdgcn_rcpf(z + 1.0f);
}

// ---------- transpose + f32->f16 convert for x/t: [b][t][h] -> [b][h][t] ----------
__global__ __launch_bounds__(256) void cvt_bth(const float* __restrict__ xin,
                                               const float* __restrict__ tin,
                                               f16* __restrict__ xo,
                                               f16* __restrict__ to) {
  __shared__ f16 tile[64][65];
  const int tid = threadIdx.x;
  const int c = tid & 63, r0 = tid >> 6;
  const int t0 = blockIdx.x * 64, h0 = blockIdx.y * 64;
  int z = blockIdx.z;
  const float* src;
  f16* dst;
  if (z < Bc) { src = xin; dst = xo; } else { src = tin; dst = to; z -= Bc; }
  src += (size_t)z * Tc * Hc;
  dst += (size_t)z * Hc * Tc;
#pragma unroll
  for (int rr = 0; rr < 64; rr += 4)
    tile[rr + r0][c] = (f16)src[(size_t)(t0 + rr + r0) * Hc + h0 + c];
  __syncthreads();
#pragma unroll
  for (int rr = 0; rr < 64; rr += 4)
    dst[(size_t)(h0 + rr + r0) * Tc + t0 + c] = tile[c][rr + r0];
}

// ---------- transpose + convert for the three TxT kernels: [t][s] -> [s][t] ----------
__global__ __launch_bounds__(256) void cvt_tt(const float* __restrict__ kx,
                                              const float* __restrict__ kt,
                                              const float* __restrict__ ka,
                                              f16* __restrict__ ox,
                                              f16* __restrict__ ot,
                                              f16* __restrict__ oa) {
  __shared__ f16 tile[64][65];
  const int tid = threadIdx.x;
  const int c = tid & 63, r0 = tid >> 6;
  const int t0 = blockIdx.x * 64, s0 = blockIdx.y * 64;
  const float* src = blockIdx.z == 0 ? kx : (blockIdx.z == 1 ? kt : ka);
  f16* dst = blockIdx.z == 0 ? ox : (blockIdx.z == 1 ? ot : oa);
#pragma unroll
  for (int rr = 0; rr < 64; rr += 4)
    tile[rr + r0][c] = (f16)src[(size_t)(t0 + rr + r0) * Tc + s0 + c];
  __syncthreads();
#pragma unroll
  for (int rr = 0; rr < 64; rr += 4)
    dst[(size_t)(s0 + rr + r0) * Tc + t0 + c] = tile[c][rr + r0];
}

// ---------- 256x256 deep-pipelined GEMM: C[m][n] = sum_k A[m][k]*B[n][k] ----------
// 8 waves (2x4), BK=32, 3 LDS buffers, counted vmcnt, XOR-swizzled LDS.
// (R2-proven schedule — two barriers/K-tile, lgkmcnt(0) drains only.)
// MODE 0: C = tanh(acc+bias[col]) f16
// MODE 1: C = lam*G + (1-lam)*tanh(acc+bias[col]) f16
// MODE 2: C = exp(acc) f32 + deterministic per-block column sums -> psums
template <int MODE>
__global__ __launch_bounds__(512, 2) void gemm_k(const f16* __restrict__ A,
                                                 const f16* __restrict__ Bm,
                                                 void* __restrict__ Cout,
                                                 const f16* __restrict__ Gprev,
                                                 const float* __restrict__ bias,
                                                 const float* __restrict__ lambd,
                                                 float* __restrict__ psums) {
  extern __shared__ char smem[];
  constexpr int BK = 32, NT = Tc / BK;            // 64 K-tiles
  constexpr int ABYTES = 256 * BK * 2;            // 16384 B per buffer
  const int tid = threadIdx.x;
  const int lane = tid & 63, w = tid >> 6;
  const int wr = w >> 2, wc = w & 3;              // 2 x 4 wave grid
  const int l15 = lane & 15, kg = lane >> 4;

  // grid: 512 blocks, XCD-bijective swizzle (512 % 8 == 0)
  int id = (int)blockIdx.x;
  id = (id & 7) * ((int)gridDim.x >> 3) + (id >> 3);
  int b, m0, n0;
  if constexpr (MODE == 2) {
    b = id >> 4; m0 = ((id >> 1) & 7) * 256; n0 = (id & 1) * 256;
  } else {
    b = 0; m0 = (id >> 3) * 256; n0 = (id & 7) * 256;
  }

  const size_t K = Tc;
  const size_t HT = (size_t)Hc * Tc;
  const f16* Ag = A + (size_t)m0 * K;
  const f16* Bg = Bm + (MODE == 2 ? (size_t)b * HT : (size_t)0) + (size_t)n0 * K;

  // staging: wave w call j stages tile rows 16*(2w+j)..+15 (1 KiB linear LDS);
  // global source pre-swizzled: chunk c = (lane&3) ^ ((lane>>3)&3)
  const int r4 = lane >> 2;
  const int cswz = ((lane & 3) ^ ((lane >> 3) & 3)) * 8;
  const int sr0 = (w * 2 + 0) * 16 + r4, sr1 = (w * 2 + 1) * 16 + r4;
  const f16* gA0 = Ag + (size_t)sr0 * K + cswz;
  const f16* gA1 = Ag + (size_t)sr1 * K + cswz;
  const f16* gB0 = Bg + (size_t)sr0 * K + cswz;
  const f16* gB1 = Bg + (size_t)sr1 * K + cswz;
  char* lA = smem;                 // 3 * 16384
  char* lB = smem + 3 * ABYTES;    // 3 * 16384
  const int lo0 = (w * 2 + 0) * 1024, lo1 = (w * 2 + 1) * 1024;

  // ds_read fragment addressing, swizzled: chunk' = kg ^ ((l15>>1)&3)
  const int xk = (kg ^ ((l15 >> 1) & 3)) * 16;
  const int aoff = (wr * 128 + l15) * 64 + xk;    // + i*1024 per M-frag
  const int boff = (wc * 64 + l15) * 64 + xk;     // + j*1024 per N-frag

  f32x4 acc[8][4];
#pragma unroll
  for (int i = 0; i < 8; ++i)
#pragma unroll
    for (int j = 0; j < 4; ++j) acc[i][j] = {0.f, 0.f, 0.f, 0.f};

  // prologue: stage tiles 0 and 1
  {
    char* d0A = lA + 0 * ABYTES; char* d0B = lB + 0 * ABYTES;
    char* d1A = lA + 1 * ABYTES; char* d1B = lB + 1 * ABYTES;
    gload_lds16(gA0, d0A + lo0); gload_lds16(gA1, d0A + lo1);
    gload_lds16(gB0, d0B + lo0); gload_lds16(gB1, d0B + lo1);
    gload_lds16(gA0 + BK, d1A + lo0); gload_lds16(gA1 + BK, d1A + lo1);
    gload_lds16(gB0 + BK, d1B + lo0); gload_lds16(gB1 + BK, d1B + lo1);
  }
  asm volatile("s_waitcnt vmcnt(4)" ::: "memory");  // tile 0 landed; tile 1 in flight
  block_barrier();

  for (int t = 0; t < NT; ++t) {
    char* curA = lA + (t % 3) * ABYTES;
    char* curB = lB + (t % 3) * ABYTES;
    const int tn = t + 2;
    char* nA = lA + (tn % 3) * ABYTES;
    char* nB = lB + (tn % 3) * ABYTES;

    // ---- phase 1: B-frags + A-frags 0..3, stage A(t+2) ----
    f16x8 bf[4], af[4];
#pragma unroll
    for (int j = 0; j < 4; ++j) bf[j] = *(const f16x8*)(curB + boff + j * 1024);
#pragma unroll
    for (int i = 0; i < 4; ++i) af[i] = *(const f16x8*)(curA + aoff + i * 1024);
    if (tn < NT) {
      gload_lds16(gA0 + (size_t)tn * BK, nA + lo0);
      gload_lds16(gA1 + (size_t)tn * BK, nA + lo1);
    }
    block_barrier();
    asm volatile("s_waitcnt lgkmcnt(0)" ::: "memory");
    __builtin_amdgcn_sched_barrier(0);
    __builtin_amdgcn_s_setprio(1);
#pragma unroll
    for (int i = 0; i < 4; ++i)
#pragma unroll
      for (int j = 0; j < 4; ++j)
        acc[i][j] = __builtin_amdgcn_mfma_f32_16x16x32_f16(af[i], bf[j], acc[i][j], 0, 0, 0);
    __builtin_amdgcn_s_setprio(0);
    block_barrier();

    // ---- phase 2: A-frags 4..7, stage B(t+2), end-of-tile counted vmcnt ----
    f16x8 ag[4];
#pragma unroll
    for (int i = 0; i < 4; ++i) ag[i] = *(const f16x8*)(curA + aoff + (4 + i) * 1024);
    if (tn < NT) {
      gload_lds16(gB0 + (size_t)tn * BK, nB + lo0);
      gload_lds16(gB1 + (size_t)tn * BK, nB + lo1);
    }
    if (t < NT - 2) {
      asm volatile("s_waitcnt vmcnt(4)" ::: "memory");  // tile t+1 landed; t+2 in flight
    } else {
      asm volatile("s_waitcnt vmcnt(0)" ::: "memory");  // drain at the tail
    }
    block_barrier();
    asm volatile("s_waitcnt lgkmcnt(0)" ::: "memory");
    __builtin_amdgcn_sched_barrier(0);
    __builtin_amdgcn_s_setprio(1);
#pragma unroll
    for (int i = 0; i < 4; ++i)
#pragma unroll
      for (int j = 0; j < 4; ++j)
        acc[4 + i][j] = __builtin_amdgcn_mfma_f32_16x16x32_f16(ag[i], bf[j], acc[4 + i][j], 0, 0, 0);
    __builtin_amdgcn_s_setprio(0);
    block_barrier();
  }

  // ---- epilogue (hardware-exp transcendentals) ----
  float psum[4] = {0.f, 0.f, 0.f, 0.f};
#pragma unroll
  for (int i = 0; i < 8; ++i) {
#pragma unroll
    for (int r = 0; r < 4; ++r) {
      const int gr = m0 + wr * 128 + i * 16 + kg * 4 + r;
#pragma unroll
      for (int j = 0; j < 4; ++j) {
        const int gc = n0 + wc * 64 + j * 16 + l15;
        const float v = acc[i][j][r];
        if constexpr (MODE == 0) {
          f16* C = (f16*)Cout;
          C[(size_t)gr * Tc + gc] = (f16)fast_tanh(v + bias[gc]);
        } else if constexpr (MODE == 1) {
          f16* C = (f16*)Cout;
          const size_t idx = (size_t)gr * Tc + gc;
          const float g = (float)Gprev[idx];
          const float lam = lambd[gr & 511];
          C[idx] = (f16)(lam * g + (1.f - lam) * fast_tanh(v + bias[gc]));
        } else {
          // no-max softmax numerator: logits are O(1), exp cannot overflow;
          // softmax is shift-invariant so this matches the reference.
          float* C = (float*)Cout;
          const float e = fast_exp(v);
          C[(size_t)b * Tc * Hc + (size_t)gr * Hc + gc] = e;
          psum[j] += e;
        }
      }
    }
  }
  if constexpr (MODE == 2) {
    // deterministic column-sum reduction: 8 partial rows x 256 cols, bijective slots
    float* ps = (float*)smem;  // K-loop LDS dead past the final barrier
#pragma unroll
    for (int j = 0; j < 4; ++j)
      ps[(wr * 4 + kg) * 256 + (wc * 64 + j * 16 + l15)] = psum[j];
    __syncthreads();
    if (tid < 256) {
      float s = 0.f;
#pragma unroll
      for (int p = 0; p < 8; ++p) s += ps[p * 256 + tid];
      psums[((size_t)b * 8 + (m0 >> 8)) * Hc + n0 + tid] = s;
    }
  }
}

// ---------- normalize: out[b][s'][h] *= 1 / sum_p psums[b][p][h] ----------
__global__ __launch_bounds__(1024) void norm_k(float* __restrict__ L,
                                               const float* __restrict__ psums) {
  const int tid = threadIdx.x;
  const int q = tid & 15, seg = tid >> 4;        // 16 h-quads x 64 T-segments
  const int b = blockIdx.x >> 3, hg = blockIdx.x & 7;
  const int h = hg * 64 + q * 4;
  const float* P = psums + (size_t)b * 8 * Hc + h;
  float s0 = 0.f, s1 = 0.f, s2 = 0.f, s3 = 0.f;
#pragma unroll
  for (int p = 0; p < 8; ++p) {
    s0 += P[p * Hc + 0]; s1 += P[p * Hc + 1];
    s2 += P[p * Hc + 2]; s3 += P[p * Hc + 3];
  }
  const float i0 = 1.f / s0, i1 = 1.f / s1, i2 = 1.f / s2, i3 = 1.f / s3;
  float* base = L + (size_t)b * Tc * Hc + h;
#pragma unroll 4
  for (int i = 0; i < 32; ++i) {
    const size_t idx = (size_t)(seg * 32 + i) * Hc;
    float4 v = *(float4*)(base + idx);
    v.x *= i0; v.y *= i1; v.z *= i2; v.w *= i3;
    *(float4*)(base + idx) = v;
  }
}

extern "C" void kernel_launch(void* const* d_in, const int* in_sizes, int n_in,
                              void* d_out, int out_size, void* d_ws, size_t ws_size,
                              hipStream_t stream) {
  const float* x  = (const float*)d_in[0];
  const float* tt = (const float*)d_in[1];
  const float* kx = (const float*)d_in[2];
  const float* kt = (const float*)d_in[3];
  const float* ka = (const float*)d_in[4];
  const float* bx = (const float*)d_in[5];
  const float* bt = (const float*)d_in[6];
  const float* lm = (const float*)d_in[7];
  float* out = (float*)d_out;

  const size_t NBHT = (size_t)Bc * Hc * Tc;  // 33,554,432 elements

  // d_out doubles as scratch for the f16-transposed inputs until gemm3 overwrites it
  f16* XhT = (f16*)d_out;
  f16* ThT = XhT + NBHT;

  // workspace: Gt(64MiB) Dt(64MiB) KxT(8) KtT(8) KaT(8)
  f16* Gt  = (f16*)d_ws;
  f16* Dt  = Gt + NBHT;
  f16* KxT = Dt + NBHT;
  f16* KtT = KxT + (size_t)Tc * Tc;
  f16* KaT = KtT + (size_t)Tc * Tc;
  // psums[32][8][512] f32 (512 KiB) reuses KxT, dead after gemm_k<0>
  float* Ps = (float*)KxT;

  constexpr int LDS_BYTES = 6 * 256 * 32 * 2;  // 98304
  (void)hipFuncSetAttribute(reinterpret_cast<const void*>(gemm_k<0>),
                            hipFuncAttributeMaxDynamicSharedMemorySize, LDS_BYTES);
  (void)hipFuncSetAttribute(reinterpret_cast<const void*>(gemm_k<1>),
                            hipFuncAttributeMaxDynamicSharedMemorySize, LDS_BYTES);
  (void)hipFuncSetAttribute(reinterpret_cast<const void*>(gemm_k<2>),
                            hipFuncAttributeMaxDynamicSharedMemorySize, LDS_BYTES);

  cvt_bth<<<dim3(Tc / 64, Hc / 64, Bc * 2), 256, 0, stream>>>(x, tt, XhT, ThT);
  cvt_tt<<<dim3(Tc / 64, Tc / 64, 3), 256, 0, stream>>>(kx, kt, ka, KxT, KtT, KaT);
  // modes 0/1: M = 32*512 = 16384 merged over batch, N = 2048 -> 64x8 = 512 blocks
  gemm_k<0><<<512, 512, LDS_BYTES, stream>>>(XhT, KxT, Gt, nullptr, bx, nullptr, nullptr);
  gemm_k<1><<<512, 512, LDS_BYTES, stream>>>(ThT, KtT, Dt, Gt, bt, lm, nullptr);
  // mode 2: per batch M = 2048, N = 512 -> 8x2 x 32 = 512 blocks
  gemm_k<2><<<512, 512, LDS_BYTES, stream>>>(KaT, Dt, out, nullptr, nullptr, nullptr, Ps);
  norm_k<<<dim3(Bc * Hc / 64), 1024, 0, stream>>>(out, Ps);
}

// Round 6
// 588.144 us; speedup vs baseline: 1.4892x; 1.0004x over previous
//
#include <hip/hip_runtime.h>

constexpr int Bc = 32, Tc = 2048, Hc = 512;

typedef _Float16 f16;
typedef _Float16 f16x8 __attribute__((ext_vector_type(8)));
typedef float f32x4 __attribute__((ext_vector_type(4)));

__device__ __forceinline__ void gload_lds16(const void* g, void* l) {
  __builtin_amdgcn_global_load_lds(
      (const __attribute__((address_space(1))) void*)g,
      (__attribute__((address_space(3))) void*)l, 16, 0, 0);
}

__device__ __forceinline__ void block_barrier() {
  __builtin_amdgcn_sched_barrier(0);
  asm volatile("" ::: "memory");
  __builtin_amdgcn_s_barrier();
  asm volatile("" ::: "memory");
  __builtin_amdgcn_sched_barrier(0);
}

// hardware-exp math: v_exp_f32 is 2^x, ~1 ulp
__device__ __forceinline__ float fast_exp(float x) {
  return __builtin_amdgcn_exp2f(x * 1.4426950408889634f);
}
__device__ __forceinline__ float fast_tanh(float x) {
  const float z = __builtin_amdgcn_exp2f(x * 2.8853900817779268f);  // e^(2x)
  return (z - 1.0f) * __builtin_amdgcn_rcpf(z + 1.0f);
}

// ---------- transpose + f32->f16 convert for x/t: [b][t][h] -> [b][h][t] ----------
__global__ __launch_bounds__(256) void cvt_bth(const float* __restrict__ xin,
                                               const float* __restrict__ tin,
                                               f16* __restrict__ xo,
                                               f16* __restrict__ to) {
  __shared__ f16 tile[64][65];
  const int tid = threadIdx.x;
  const int c = tid & 63, r0 = tid >> 6;
  const int t0 = blockIdx.x * 64, h0 = blockIdx.y * 64;
  int z = blockIdx.z;
  const float* src;
  f16* dst;
  if (z < Bc) { src = xin; dst = xo; } else { src = tin; dst = to; z -= Bc; }
  src += (size_t)z * Tc * Hc;
  dst += (size_t)z * Hc * Tc;
#pragma unroll
  for (int rr = 0; rr < 64; rr += 4)
    tile[rr + r0][c] = (f16)src[(size_t)(t0 + rr + r0) * Hc + h0 + c];
  __syncthreads();
#pragma unroll
  for (int rr = 0; rr < 64; rr += 4)
    dst[(size_t)(h0 + rr + r0) * Tc + t0 + c] = tile[c][rr + r0];
}

// ---------- transpose + convert for the three TxT kernels: [t][s] -> [s][t] ----------
__global__ __launch_bounds__(256) void cvt_tt(const float* __restrict__ kx,
                                              const float* __restrict__ kt,
                                              const float* __restrict__ ka,
                                              f16* __restrict__ ox,
                                              f16* __restrict__ ot,
                                              f16* __restrict__ oa) {
  __shared__ f16 tile[64][65];
  const int tid = threadIdx.x;
  const int c = tid & 63, r0 = tid >> 6;
  const int t0 = blockIdx.x * 64, s0 = blockIdx.y * 64;
  const float* src = blockIdx.z == 0 ? kx : (blockIdx.z == 1 ? kt : ka);
  f16* dst = blockIdx.z == 0 ? ox : (blockIdx.z == 1 ? ot : oa);
#pragma unroll
  for (int rr = 0; rr < 64; rr += 4)
    tile[rr + r0][c] = (f16)src[(size_t)(t0 + rr + r0) * Tc + s0 + c];
  __syncthreads();
#pragma unroll
  for (int rr = 0; rr < 64; rr += 4)
    dst[(size_t)(s0 + rr + r0) * Tc + t0 + c] = tile[c][rr + r0];
}

// ---------- 256x256 deep-pipelined GEMM: C[m][n] = sum_k A[m][k]*B[n][k] ----------
// 8 waves (2x4), BK=32, FOUR LDS buffers (prefetch distance 3), counted vmcnt(8),
// XOR-swizzled LDS. Same 2-barrier-per-phase schedule as the proven R2 kernel.
// MODE 0: C = tanh(acc+bias[col]) f16
// MODE 1: C = lam*G + (1-lam)*tanh(acc+bias[col]) f16
// MODE 2: C = exp(acc) f32 + deterministic per-block column sums -> psums
template <int MODE>
__global__ __launch_bounds__(512, 2) void gemm_k(const f16* __restrict__ A,
                                                 const f16* __restrict__ Bm,
                                                 void* __restrict__ Cout,
                                                 const f16* __restrict__ Gprev,
                                                 const float* __restrict__ bias,
                                                 const float* __restrict__ lambd,
                                                 float* __restrict__ psums) {
  extern __shared__ char smem[];
  constexpr int BK = 32, NT = Tc / BK;            // 64 K-tiles
  constexpr int ABYTES = 256 * BK * 2;            // 16384 B per buffer
  const int tid = threadIdx.x;
  const int lane = tid & 63, w = tid >> 6;
  const int wr = w >> 2, wc = w & 3;              // 2 x 4 wave grid
  const int l15 = lane & 15, kg = lane >> 4;

  // grid: 512 blocks, XCD-bijective swizzle (512 % 8 == 0)
  int id = (int)blockIdx.x;
  id = (id & 7) * ((int)gridDim.x >> 3) + (id >> 3);
  int b, m0, n0;
  if constexpr (MODE == 2) {
    b = id >> 4; m0 = ((id >> 1) & 7) * 256; n0 = (id & 1) * 256;
  } else {
    b = 0; m0 = (id >> 3) * 256; n0 = (id & 7) * 256;
  }

  const size_t K = Tc;
  const size_t HT = (size_t)Hc * Tc;
  const f16* Ag = A + (size_t)m0 * K;
  const f16* Bg = Bm + (MODE == 2 ? (size_t)b * HT : (size_t)0) + (size_t)n0 * K;

  // staging: wave w call j stages tile rows 16*(2w+j)..+15 (1 KiB linear LDS);
  // global source pre-swizzled: chunk c = (lane&3) ^ ((lane>>3)&3)
  const int r4 = lane >> 2;
  const int cswz = ((lane & 3) ^ ((lane >> 3) & 3)) * 8;
  const int sr0 = (w * 2 + 0) * 16 + r4, sr1 = (w * 2 + 1) * 16 + r4;
  const f16* gA0 = Ag + (size_t)sr0 * K + cswz;
  const f16* gA1 = Ag + (size_t)sr1 * K + cswz;
  const f16* gB0 = Bg + (size_t)sr0 * K + cswz;
  const f16* gB1 = Bg + (size_t)sr1 * K + cswz;
  char* lA = smem;                 // 4 * 16384
  char* lB = smem + 4 * ABYTES;    // 4 * 16384
  const int lo0 = (w * 2 + 0) * 1024, lo1 = (w * 2 + 1) * 1024;

  // ds_read fragment addressing, swizzled: chunk' = kg ^ ((l15>>1)&3)
  const int xk = (kg ^ ((l15 >> 1) & 3)) * 16;
  const int aoff = (wr * 128 + l15) * 64 + xk;    // + i*1024 per M-frag
  const int boff = (wc * 64 + l15) * 64 + xk;     // + j*1024 per N-frag

  f32x4 acc[8][4];
#pragma unroll
  for (int i = 0; i < 8; ++i)
#pragma unroll
    for (int j = 0; j < 4; ++j) acc[i][j] = {0.f, 0.f, 0.f, 0.f};

  // prologue: stage tiles 0,1,2 (A then B per tile; 12 loads total)
#pragma unroll
  for (int p = 0; p < 3; ++p) {
    char* dA = lA + p * ABYTES;
    char* dB = lB + p * ABYTES;
    gload_lds16(gA0 + (size_t)p * BK, dA + lo0);
    gload_lds16(gA1 + (size_t)p * BK, dA + lo1);
    gload_lds16(gB0 + (size_t)p * BK, dB + lo0);
    gload_lds16(gB1 + (size_t)p * BK, dB + lo1);
  }
  asm volatile("s_waitcnt vmcnt(8)" ::: "memory");  // tile 0 landed; 1,2 in flight
  block_barrier();

  for (int t = 0; t < NT; ++t) {
    char* curA = lA + (t & 3) * ABYTES;
    char* curB = lB + (t & 3) * ABYTES;
    const int tn = t + 3;                            // prefetch distance 3
    char* nA = lA + (tn & 3) * ABYTES;
    char* nB = lB + (tn & 3) * ABYTES;

    // ---- phase 1: B-frags + A-frags 0..3, stage A(t+3) ----
    f16x8 bf[4], af[4];
#pragma unroll
    for (int j = 0; j < 4; ++j) bf[j] = *(const f16x8*)(curB + boff + j * 1024);
#pragma unroll
    for (int i = 0; i < 4; ++i) af[i] = *(const f16x8*)(curA + aoff + i * 1024);
    if (tn < NT) {
      gload_lds16(gA0 + (size_t)tn * BK, nA + lo0);
      gload_lds16(gA1 + (size_t)tn * BK, nA + lo1);
    }
    block_barrier();
    asm volatile("s_waitcnt lgkmcnt(0)" ::: "memory");
    __builtin_amdgcn_sched_barrier(0);
    __builtin_amdgcn_s_setprio(1);
#pragma unroll
    for (int i = 0; i < 4; ++i)
#pragma unroll
      for (int j = 0; j < 4; ++j)
        acc[i][j] = __builtin_amdgcn_mfma_f32_16x16x32_f16(af[i], bf[j], acc[i][j], 0, 0, 0);
    __builtin_amdgcn_s_setprio(0);
    block_barrier();

    // ---- phase 2: A-frags 4..7, stage B(t+3), end-of-tile counted vmcnt ----
    f16x8 ag[4];
#pragma unroll
    for (int i = 0; i < 4; ++i) ag[i] = *(const f16x8*)(curA + aoff + (4 + i) * 1024);
    if (tn < NT) {
      gload_lds16(gB0 + (size_t)tn * BK, nB + lo0);
      gload_lds16(gB1 + (size_t)tn * BK, nB + lo1);
    }
    // queue (oldest first): A/B(t+1), A/B(t+2), A/B(t+3) = 12 loads.
    // need t+1 landed -> vmcnt(8); tail: NT-3 -> 4, later -> 0.
    if (t < NT - 3) {
      asm volatile("s_waitcnt vmcnt(8)" ::: "memory");
    } else if (t == NT - 3) {
      asm volatile("s_waitcnt vmcnt(4)" ::: "memory");
    } else {
      asm volatile("s_waitcnt vmcnt(0)" ::: "memory");
    }
    block_barrier();
    asm volatile("s_waitcnt lgkmcnt(0)" ::: "memory");
    __builtin_amdgcn_sched_barrier(0);
    __builtin_amdgcn_s_setprio(1);
#pragma unroll
    for (int i = 0; i < 4; ++i)
#pragma unroll
      for (int j = 0; j < 4; ++j)
        acc[4 + i][j] = __builtin_amdgcn_mfma_f32_16x16x32_f16(ag[i], bf[j], acc[4 + i][j], 0, 0, 0);
    __builtin_amdgcn_s_setprio(0);
    block_barrier();
  }

  // ---- epilogue (hardware-exp transcendentals) ----
  float psum[4] = {0.f, 0.f, 0.f, 0.f};
#pragma unroll
  for (int i = 0; i < 8; ++i) {
#pragma unroll
    for (int r = 0; r < 4; ++r) {
      const int gr = m0 + wr * 128 + i * 16 + kg * 4 + r;
#pragma unroll
      for (int j = 0; j < 4; ++j) {
        const int gc = n0 + wc * 64 + j * 16 + l15;
        const float v = acc[i][j][r];
        if constexpr (MODE == 0) {
          f16* C = (f16*)Cout;
          C[(size_t)gr * Tc + gc] = (f16)fast_tanh(v + bias[gc]);
        } else if constexpr (MODE == 1) {
          f16* C = (f16*)Cout;
          const size_t idx = (size_t)gr * Tc + gc;
          const float g = (float)Gprev[idx];
          const float lam = lambd[gr & 511];
          C[idx] = (f16)(lam * g + (1.f - lam) * fast_tanh(v + bias[gc]));
        } else {
          // no-max softmax numerator: logits are O(1), exp cannot overflow;
          // softmax is shift-invariant so this matches the reference.
          float* C = (float*)Cout;
          const float e = fast_exp(v);
          C[(size_t)b * Tc * Hc + (size_t)gr * Hc + gc] = e;
          psum[j] += e;
        }
      }
    }
  }
  if constexpr (MODE == 2) {
    // deterministic column-sum reduction: 8 partial rows x 256 cols, bijective slots
    float* ps = (float*)smem;  // K-loop LDS dead past the final barrier
#pragma unroll
    for (int j = 0; j < 4; ++j)
      ps[(wr * 4 + kg) * 256 + (wc * 64 + j * 16 + l15)] = psum[j];
    __syncthreads();
    if (tid < 256) {
      float s = 0.f;
#pragma unroll
      for (int p = 0; p < 8; ++p) s += ps[p * 256 + tid];
      psums[((size_t)b * 8 + (m0 >> 8)) * Hc + n0 + tid] = s;
    }
  }
}

// ---------- normalize: out[b][s'][h] *= 1 / sum_p psums[b][p][h] ----------
__global__ __launch_bounds__(1024) void norm_k(float* __restrict__ L,
                                               const float* __restrict__ psums) {
  const int tid = threadIdx.x;
  const int q = tid & 15, seg = tid >> 4;        // 16 h-quads x 64 T-segments
  const int b = blockIdx.x >> 3, hg = blockIdx.x & 7;
  const int h = hg * 64 + q * 4;
  const float* P = psums + (size_t)b * 8 * Hc + h;
  float s0 = 0.f, s1 = 0.f, s2 = 0.f, s3 = 0.f;
#pragma unroll
  for (int p = 0; p < 8; ++p) {
    s0 += P[p * Hc + 0]; s1 += P[p * Hc + 1];
    s2 += P[p * Hc + 2]; s3 += P[p * Hc + 3];
  }
  const float i0 = 1.f / s0, i1 = 1.f / s1, i2 = 1.f / s2, i3 = 1.f / s3;
  float* base = L + (size_t)b * Tc * Hc + h;
#pragma unroll 4
  for (int i = 0; i < 32; ++i) {
    const size_t idx = (size_t)(seg * 32 + i) * Hc;
    float4 v = *(float4*)(base + idx);
    v.x *= i0; v.y *= i1; v.z *= i2; v.w *= i3;
    *(float4*)(base + idx) = v;
  }
}

extern "C" void kernel_launch(void* const* d_in, const int* in_sizes, int n_in,
                              void* d_out, int out_size, void* d_ws, size_t ws_size,
                              hipStream_t stream) {
  const float* x  = (const float*)d_in[0];
  const float* tt = (const float*)d_in[1];
  const float* kx = (const float*)d_in[2];
  const float* kt = (const float*)d_in[3];
  const float* ka = (const float*)d_in[4];
  const float* bx = (const float*)d_in[5];
  const float* bt = (const float*)d_in[6];
  const float* lm = (const float*)d_in[7];
  float* out = (float*)d_out;

  const size_t NBHT = (size_t)Bc * Hc * Tc;  // 33,554,432 elements

  // d_out doubles as scratch for the f16-transposed inputs until gemm3 overwrites it
  f16* XhT = (f16*)d_out;
  f16* ThT = XhT + NBHT;

  // workspace: Gt(64MiB) Dt(64MiB) KxT(8) KtT(8) KaT(8)
  f16* Gt  = (f16*)d_ws;
  f16* Dt  = Gt + NBHT;
  f16* KxT = Dt + NBHT;
  f16* KtT = KxT + (size_t)Tc * Tc;
  f16* KaT = KtT + (size_t)Tc * Tc;
  // psums[32][8][512] f32 (512 KiB) reuses KxT, dead after gemm_k<0>
  float* Ps = (float*)KxT;

  constexpr int LDS_BYTES = 8 * 256 * 32 * 2;  // 131072 (4 buffers x A,B)
  (void)hipFuncSetAttribute(reinterpret_cast<const void*>(gemm_k<0>),
                            hipFuncAttributeMaxDynamicSharedMemorySize, LDS_BYTES);
  (void)hipFuncSetAttribute(reinterpret_cast<const void*>(gemm_k<1>),
                            hipFuncAttributeMaxDynamicSharedMemorySize, LDS_BYTES);
  (void)hipFuncSetAttribute(reinterpret_cast<const void*>(gemm_k<2>),
                            hipFuncAttributeMaxDynamicSharedMemorySize, LDS_BYTES);

  cvt_bth<<<dim3(Tc / 64, Hc / 64, Bc * 2), 256, 0, stream>>>(x, tt, XhT, ThT);
  cvt_tt<<<dim3(Tc / 64, Tc / 64, 3), 256, 0, stream>>>(kx, kt, ka, KxT, KtT, KaT);
  // modes 0/1: M = 32*512 = 16384 merged over batch, N = 2048 -> 64x8 = 512 blocks
  gemm_k<0><<<512, 512, LDS_BYTES, stream>>>(XhT, KxT, Gt, nullptr, bx, nullptr, nullptr);
  gemm_k<1><<<512, 512, LDS_BYTES, stream>>>(ThT, KtT, Dt, Gt, bt, lm, nullptr);
  // mode 2: per batch M = 2048, N = 512 -> 8x2 x 32 = 512 blocks
  gemm_k<2><<<512, 512, LDS_BYTES, stream>>>(KaT, Dt, out, nullptr, nullptr, nullptr, Ps);
  norm_k<<<dim3(Bc * Hc / 64), 1024, 0, stream>>>(out, Ps);
}

// Round 7
// 587.396 us; speedup vs baseline: 1.4911x; 1.0013x over previous
//
#include <hip/hip_runtime.h>

constexpr int Bc = 32, Tc = 2048, Hc = 512;

typedef _Float16 f16;
typedef _Float16 f16x8 __attribute__((ext_vector_type(8)));
typedef float f32x4 __attribute__((ext_vector_type(4)));

__device__ __forceinline__ void gload_lds16(const void* g, void* l) {
  __builtin_amdgcn_global_load_lds(
      (const __attribute__((address_space(1))) void*)g,
      (__attribute__((address_space(3))) void*)l, 16, 0, 0);
}

// hardware-exp math: v_exp_f32 is 2^x, ~1 ulp
__device__ __forceinline__ float fast_exp(float x) {
  return __builtin_amdgcn_exp2f(x * 1.4426950408889634f);
}
__device__ __forceinline__ float fast_tanh(float x) {
  const float z = __builtin_amdgcn_exp2f(x * 2.8853900817779268f);  // e^(2x)
  return (z - 1.0f) * __builtin_amdgcn_rcpf(z + 1.0f);
}

// ---------- transpose + f32->f16 convert for x/t: [b][t][h] -> [b][h][t] ----------
__global__ __launch_bounds__(256) void cvt_bth(const float* __restrict__ xin,
                                               const float* __restrict__ tin,
                                               f16* __restrict__ xo,
                                               f16* __restrict__ to) {
  __shared__ f16 tile[64][65];
  const int tid = threadIdx.x;
  const int c = tid & 63, r0 = tid >> 6;
  const int t0 = blockIdx.x * 64, h0 = blockIdx.y * 64;
  int z = blockIdx.z;
  const float* src;
  f16* dst;
  if (z < Bc) { src = xin; dst = xo; } else { src = tin; dst = to; z -= Bc; }
  src += (size_t)z * Tc * Hc;
  dst += (size_t)z * Hc * Tc;
#pragma unroll
  for (int rr = 0; rr < 64; rr += 4)
    tile[rr + r0][c] = (f16)src[(size_t)(t0 + rr + r0) * Hc + h0 + c];
  __syncthreads();
#pragma unroll
  for (int rr = 0; rr < 64; rr += 4)
    dst[(size_t)(h0 + rr + r0) * Tc + t0 + c] = tile[c][rr + r0];
}

// ---------- transpose + convert for the three TxT kernels: [t][s] -> [s][t] ----------
__global__ __launch_bounds__(256) void cvt_tt(const float* __restrict__ kx,
                                              const float* __restrict__ kt,
                                              const float* __restrict__ ka,
                                              f16* __restrict__ ox,
                                              f16* __restrict__ ot,
                                              f16* __restrict__ oa) {
  __shared__ f16 tile[64][65];
  const int tid = threadIdx.x;
  const int c = tid & 63, r0 = tid >> 6;
  const int t0 = blockIdx.x * 64, s0 = blockIdx.y * 64;
  const float* src = blockIdx.z == 0 ? kx : (blockIdx.z == 1 ? kt : ka);
  f16* dst = blockIdx.z == 0 ? ox : (blockIdx.z == 1 ? ot : oa);
#pragma unroll
  for (int rr = 0; rr < 64; rr += 4)
    tile[rr + r0][c] = (f16)src[(size_t)(t0 + rr + r0) * Tc + s0 + c];
  __syncthreads();
#pragma unroll
  for (int rr = 0; rr < 64; rr += 4)
    dst[(size_t)(s0 + rr + r0) * Tc + t0 + c] = tile[c][rr + r0];
}

// ---------- 256x256 deep-pipelined GEMM: C[m][n] = sum_k A[m][k]*B[n][k] ----------
// 8 waves (2x4), BK=32, 4 LDS buffers (prefetch distance 3), counted vmcnt(8),
// XOR-swizzled LDS. LOOSE m201-style fences: bare s_barrier, non-clobbering
// waitcnt asm — lets the compiler overlap ds_read issue/delivery with MFMA.
// MODE 0: C = tanh(acc+bias[col]) f16
// MODE 1: C = lam*G + (1-lam)*tanh(acc+bias[col]) f16
// MODE 2: C = exp(acc) f32 + deterministic per-block column sums -> psums
template <int MODE>
__global__ __launch_bounds__(512, 2) void gemm_k(const f16* __restrict__ A,
                                                 const f16* __restrict__ Bm,
                                                 void* __restrict__ Cout,
                                                 const f16* __restrict__ Gprev,
                                                 const float* __restrict__ bias,
                                                 const float* __restrict__ lambd,
                                                 float* __restrict__ psums) {
  extern __shared__ char smem[];
  constexpr int BK = 32, NT = Tc / BK;            // 64 K-tiles
  constexpr int ABYTES = 256 * BK * 2;            // 16384 B per buffer
  const int tid = threadIdx.x;
  const int lane = tid & 63, w = tid >> 6;
  const int wr = w >> 2, wc = w & 3;              // 2 x 4 wave grid
  const int l15 = lane & 15, kg = lane >> 4;

  // grid: 512 blocks, XCD-bijective swizzle (512 % 8 == 0)
  int id = (int)blockIdx.x;
  id = (id & 7) * ((int)gridDim.x >> 3) + (id >> 3);
  int b, m0, n0;
  if constexpr (MODE == 2) {
    b = id >> 4; m0 = ((id >> 1) & 7) * 256; n0 = (id & 1) * 256;
  } else {
    b = 0; m0 = (id >> 3) * 256; n0 = (id & 7) * 256;
  }

  const size_t K = Tc;
  const size_t HT = (size_t)Hc * Tc;
  const f16* Ag = A + (size_t)m0 * K;
  const f16* Bg = Bm + (MODE == 2 ? (size_t)b * HT : (size_t)0) + (size_t)n0 * K;

  // staging: wave w call j stages tile rows 16*(2w+j)..+15 (1 KiB linear LDS);
  // global source pre-swizzled: chunk c = (lane&3) ^ ((lane>>3)&3)
  const int r4 = lane >> 2;
  const int cswz = ((lane & 3) ^ ((lane >> 3) & 3)) * 8;
  const int sr0 = (w * 2 + 0) * 16 + r4, sr1 = (w * 2 + 1) * 16 + r4;
  const f16* gA0 = Ag + (size_t)sr0 * K + cswz;
  const f16* gA1 = Ag + (size_t)sr1 * K + cswz;
  const f16* gB0 = Bg + (size_t)sr0 * K + cswz;
  const f16* gB1 = Bg + (size_t)sr1 * K + cswz;
  char* lA = smem;                 // 4 * 16384
  char* lB = smem + 4 * ABYTES;    // 4 * 16384
  const int lo0 = (w * 2 + 0) * 1024, lo1 = (w * 2 + 1) * 1024;

  // ds_read fragment addressing, swizzled: chunk' = kg ^ ((l15>>1)&3)
  const int xk = (kg ^ ((l15 >> 1) & 3)) * 16;
  const int aoff = (wr * 128 + l15) * 64 + xk;    // + i*1024 per M-frag
  const int boff = (wc * 64 + l15) * 64 + xk;     // + j*1024 per N-frag

  f32x4 acc[8][4];
#pragma unroll
  for (int i = 0; i < 8; ++i)
#pragma unroll
    for (int j = 0; j < 4; ++j) acc[i][j] = {0.f, 0.f, 0.f, 0.f};

  // prologue: stage tiles 0,1,2 (A then B per tile; 12 loads total)
#pragma unroll
  for (int p = 0; p < 3; ++p) {
    char* dA = lA + p * ABYTES;
    char* dB = lB + p * ABYTES;
    gload_lds16(gA0 + (size_t)p * BK, dA + lo0);
    gload_lds16(gA1 + (size_t)p * BK, dA + lo1);
    gload_lds16(gB0 + (size_t)p * BK, dB + lo0);
    gload_lds16(gB1 + (size_t)p * BK, dB + lo1);
  }
  asm volatile("s_waitcnt vmcnt(8)");  // tile 0 landed; 1,2 in flight
  __builtin_amdgcn_s_barrier();

  for (int t = 0; t < NT; ++t) {
    char* curA = lA + (t & 3) * ABYTES;
    char* curB = lB + (t & 3) * ABYTES;
    const int tn = t + 3;                            // prefetch distance 3
    char* nA = lA + (tn & 3) * ABYTES;
    char* nB = lB + (tn & 3) * ABYTES;

    // ---- phase 1: B-frags + A-frags 0..3, stage A(t+3) ----
    f16x8 bf[4], af[4];
#pragma unroll
    for (int j = 0; j < 4; ++j) bf[j] = *(const f16x8*)(curB + boff + j * 1024);
#pragma unroll
    for (int i = 0; i < 4; ++i) af[i] = *(const f16x8*)(curA + aoff + i * 1024);
    if (tn < NT) {
      gload_lds16(gA0 + (size_t)tn * BK, nA + lo0);
      gload_lds16(gA1 + (size_t)tn * BK, nA + lo1);
    }
    __builtin_amdgcn_s_barrier();
    asm volatile("s_waitcnt lgkmcnt(0)");
    __builtin_amdgcn_s_setprio(1);
#pragma unroll
    for (int i = 0; i < 4; ++i)
#pragma unroll
      for (int j = 0; j < 4; ++j)
        acc[i][j] = __builtin_amdgcn_mfma_f32_16x16x32_f16(af[i], bf[j], acc[i][j], 0, 0, 0);
    __builtin_amdgcn_s_setprio(0);
    __builtin_amdgcn_s_barrier();

    // ---- phase 2: A-frags 4..7, stage B(t+3), end-of-tile counted vmcnt ----
    f16x8 ag[4];
#pragma unroll
    for (int i = 0; i < 4; ++i) ag[i] = *(const f16x8*)(curA + aoff + (4 + i) * 1024);
    if (tn < NT) {
      gload_lds16(gB0 + (size_t)tn * BK, nB + lo0);
      gload_lds16(gB1 + (size_t)tn * BK, nB + lo1);
    }
    // queue (oldest first): A/B(t+1), A/B(t+2), A/B(t+3) = 12 loads.
    // need t+1 landed -> vmcnt(8); tail: NT-3 -> 4, later -> 0.
    if (t < NT - 3) {
      asm volatile("s_waitcnt vmcnt(8)");
    } else if (t == NT - 3) {
      asm volatile("s_waitcnt vmcnt(4)");
    } else {
      asm volatile("s_waitcnt vmcnt(0)");
    }
    __builtin_amdgcn_s_barrier();
    asm volatile("s_waitcnt lgkmcnt(0)");
    __builtin_amdgcn_s_setprio(1);
#pragma unroll
    for (int i = 0; i < 4; ++i)
#pragma unroll
      for (int j = 0; j < 4; ++j)
        acc[4 + i][j] = __builtin_amdgcn_mfma_f32_16x16x32_f16(ag[i], bf[j], acc[4 + i][j], 0, 0, 0);
    __builtin_amdgcn_s_setprio(0);
    __builtin_amdgcn_s_barrier();
  }

  // ---- epilogue (hardware-exp transcendentals) ----
  float psum[4] = {0.f, 0.f, 0.f, 0.f};
#pragma unroll
  for (int i = 0; i < 8; ++i) {
#pragma unroll
    for (int r = 0; r < 4; ++r) {
      const int gr = m0 + wr * 128 + i * 16 + kg * 4 + r;
#pragma unroll
      for (int j = 0; j < 4; ++j) {
        const int gc = n0 + wc * 64 + j * 16 + l15;
        const float v = acc[i][j][r];
        if constexpr (MODE == 0) {
          f16* C = (f16*)Cout;
          C[(size_t)gr * Tc + gc] = (f16)fast_tanh(v + bias[gc]);
        } else if constexpr (MODE == 1) {
          f16* C = (f16*)Cout;
          const size_t idx = (size_t)gr * Tc + gc;
          const float g = (float)Gprev[idx];
          const float lam = lambd[gr & 511];
          C[idx] = (f16)(lam * g + (1.f - lam) * fast_tanh(v + bias[gc]));
        } else {
          // no-max softmax numerator: logits are O(1), exp cannot overflow;
          // softmax is shift-invariant so this matches the reference.
          float* C = (float*)Cout;
          const float e = fast_exp(v);
          C[(size_t)b * Tc * Hc + (size_t)gr * Hc + gc] = e;
          psum[j] += e;
        }
      }
    }
  }
  if constexpr (MODE == 2) {
    // deterministic column-sum reduction: 8 partial rows x 256 cols, bijective slots
    float* ps = (float*)smem;  // K-loop LDS dead past the final barrier
    __syncthreads();
#pragma unroll
    for (int j = 0; j < 4; ++j)
      ps[(wr * 4 + kg) * 256 + (wc * 64 + j * 16 + l15)] = psum[j];
    __syncthreads();
    if (tid < 256) {
      float s = 0.f;
#pragma unroll
      for (int p = 0; p < 8; ++p) s += ps[p * 256 + tid];
      psums[((size_t)b * 8 + (m0 >> 8)) * Hc + n0 + tid] = s;
    }
  }
}

// ---------- normalize: out[b][s'][h] *= 1 / sum_p psums[b][p][h] ----------
__global__ __launch_bounds__(1024) void norm_k(float* __restrict__ L,
                                               const float* __restrict__ psums) {
  const int tid = threadIdx.x;
  const int q = tid & 15, seg = tid >> 4;        // 16 h-quads x 64 T-segments
  const int b = blockIdx.x >> 3, hg = blockIdx.x & 7;
  const int h = hg * 64 + q * 4;
  const float* P = psums + (size_t)b * 8 * Hc + h;
  float s0 = 0.f, s1 = 0.f, s2 = 0.f, s3 = 0.f;
#pragma unroll
  for (int p = 0; p < 8; ++p) {
    s0 += P[p * Hc + 0]; s1 += P[p * Hc + 1];
    s2 += P[p * Hc + 2]; s3 += P[p * Hc + 3];
  }
  const float i0 = 1.f / s0, i1 = 1.f / s1, i2 = 1.f / s2, i3 = 1.f / s3;
  float* base = L + (size_t)b * Tc * Hc + h;
#pragma unroll 4
  for (int i = 0; i < 32; ++i) {
    const size_t idx = (size_t)(seg * 32 + i) * Hc;
    float4 v = *(float4*)(base + idx);
    v.x *= i0; v.y *= i1; v.z *= i2; v.w *= i3;
    *(float4*)(base + idx) = v;
  }
}

extern "C" void kernel_launch(void* const* d_in, const int* in_sizes, int n_in,
                              void* d_out, int out_size, void* d_ws, size_t ws_size,
                              hipStream_t stream) {
  const float* x  = (const float*)d_in[0];
  const float* tt = (const float*)d_in[1];
  const float* kx = (const float*)d_in[2];
  const float* kt = (const float*)d_in[3];
  const float* ka = (const float*)d_in[4];
  const float* bx = (const float*)d_in[5];
  const float* bt = (const float*)d_in[6];
  const float* lm = (const float*)d_in[7];
  float* out = (float*)d_out;

  const size_t NBHT = (size_t)Bc * Hc * Tc;  // 33,554,432 elements

  // d_out doubles as scratch for the f16-transposed inputs until gemm3 overwrites it
  f16* XhT = (f16*)d_out;
  f16* ThT = XhT + NBHT;

  // workspace: Gt(64MiB) Dt(64MiB) KxT(8) KtT(8) KaT(8)
  f16* Gt  = (f16*)d_ws;
  f16* Dt  = Gt + NBHT;
  f16* KxT = Dt + NBHT;
  f16* KtT = KxT + (size_t)Tc * Tc;
  f16* KaT = KtT + (size_t)Tc * Tc;
  // psums[32][8][512] f32 (512 KiB) reuses KxT, dead after gemm_k<0>
  float* Ps = (float*)KxT;

  constexpr int LDS_BYTES = 8 * 256 * 32 * 2;  // 131072 (4 buffers x A,B)
  (void)hipFuncSetAttribute(reinterpret_cast<const void*>(gemm_k<0>),
                            hipFuncAttributeMaxDynamicSharedMemorySize, LDS_BYTES);
  (void)hipFuncSetAttribute(reinterpret_cast<const void*>(gemm_k<1>),
                            hipFuncAttributeMaxDynamicSharedMemorySize, LDS_BYTES);
  (void)hipFuncSetAttribute(reinterpret_cast<const void*>(gemm_k<2>),
                            hipFuncAttributeMaxDynamicSharedMemorySize, LDS_BYTES);

  cvt_bth<<<dim3(Tc / 64, Hc / 64, Bc * 2), 256, 0, stream>>>(x, tt, XhT, ThT);
  cvt_tt<<<dim3(Tc / 64, Tc / 64, 3), 256, 0, stream>>>(kx, kt, ka, KxT, KtT, KaT);
  // modes 0/1: M = 32*512 = 16384 merged over batch, N = 2048 -> 64x8 = 512 blocks
  gemm_k<0><<<512, 512, LDS_BYTES, stream>>>(XhT, KxT, Gt, nullptr, bx, nullptr, nullptr);
  gemm_k<1><<<512, 512, LDS_BYTES, stream>>>(ThT, KtT, Dt, Gt, bt, lm, nullptr);
  // mode 2: per batch M = 2048, N = 512 -> 8x2 x 32 = 512 blocks
  gemm_k<2><<<512, 512, LDS_BYTES, stream>>>(KaT, Dt, out, nullptr, nullptr, nullptr, Ps);
  norm_k<<<dim3(Bc * Hc / 64), 1024, 0, stream>>>(out, Ps);
}